// Round 11
// baseline (352.255 us; speedup 1.0000x reference)
//
#include <hip/hip_runtime.h>
#include <math.h>

#define TLEN 2000
#define NSEQ 8       // B*C
#define NHEADS 8
#define KD 32
#define CHUNKN 500
#define NCHUNK 4
#define MROWS 16000  // NSEQ*TLEN
#define SCALING 0.1767766952966369f

typedef float f32x4 __attribute__((ext_vector_type(4)));
typedef short s16x8 __attribute__((ext_vector_type(8)));
typedef unsigned short u16x8 __attribute__((ext_vector_type(8)));
typedef unsigned short u16x4 __attribute__((ext_vector_type(4)));

__device__ __forceinline__ unsigned short f2bf(float f) {
    unsigned int u = __float_as_uint(f);
    unsigned int r = (u + 0x7FFFu + ((u >> 16) & 1u)) >> 16;
    return (unsigned short)r;
}
__device__ __forceinline__ float bf2f(unsigned short h) {
    return __uint_as_float(((unsigned int)h) << 16);
}
__device__ __forceinline__ unsigned int cvtpk(float lo, float hi) {
    unsigned int r;
    asm("v_cvt_pk_bf16_f32 %0, %1, %2" : "=v"(r) : "v"(lo), "v"(hi));
    return r;
}

// ---------------------------------------------------------------- tables (16 angles)
__global__ __launch_bounds__(256) void tab_kernel(float* __restrict__ sinT,
                                                  float* __restrict__ cosT) {
    int idx = blockIdx.x * 256 + threadIdx.x;
    if (idx >= TLEN * 16) return;
    int t = idx >> 4, a = idx & 15;
    float ang = powf(10000.0f, -(float)a / 15.0f);
    float th = (float)t * ang;
    sinT[idx] = sinf(th);
    cosT[idx] = cosf(th);
}

// ---------------------------------------------------------------- weight cast fp32 -> bf16 concat
__global__ __launch_bounds__(256) void wcast_kernel(
    const float* __restrict__ qw, const float* __restrict__ kw,
    const float* __restrict__ vw, const float* __restrict__ gw,
    const float* __restrict__ ow, const float* __restrict__ inw,
    const float* __restrict__ outw, unsigned short* __restrict__ W) {
    int i = blockIdx.x * 1024 + threadIdx.x * 4;
    const float* src; int off;
    if (i < 65536)       { src = qw;   off = i; }
    else if (i < 131072) { src = kw;   off = i - 65536; }
    else if (i < 196608) { src = vw;   off = i - 131072; }
    else if (i < 262144) { src = gw;   off = i - 196608; }
    else if (i < 327680) { src = ow;   off = i - 262144; }
    else if (i < 524288) { src = inw;  off = i - 327680; }
    else                 { src = outw; off = i - 524288; }
    float4 v = *(const float4*)(src + off);
    u16x4 o;
    o[0] = f2bf(v.x); o[1] = f2bf(v.y); o[2] = f2bf(v.z); o[3] = f2bf(v.w);
    *(u16x4*)(W + i) = o;
}

// ---------------------------------------------------------------- layernorm -> bf16 hi/lo
__global__ __launch_bounds__(256) void ln_kernel(const float* __restrict__ x,
                                                 const float* __restrict__ gam,
                                                 const float* __restrict__ bet,
                                                 unsigned short* __restrict__ H,
                                                 unsigned short* __restrict__ L,
                                                 int rows) {
    int wid = threadIdx.x >> 6, lane = threadIdx.x & 63;
    int row = blockIdx.x * 4 + wid;
    if (row >= rows) return;
    const float* xr = x + (size_t)row * 256;
    float4 v = *(const float4*)(xr + lane * 4);
    float s = v.x + v.y + v.z + v.w;
    #pragma unroll
    for (int o = 32; o; o >>= 1) s += __shfl_xor(s, o);
    float mu = s * (1.0f / 256.0f);
    float dx = v.x - mu, dy = v.y - mu, dz = v.z - mu, dw = v.w - mu;
    float ss = dx * dx + dy * dy + dz * dz + dw * dw;
    #pragma unroll
    for (int o = 32; o; o >>= 1) ss += __shfl_xor(ss, o);
    float rstd = rsqrtf(ss * (1.0f / 256.0f) + 1e-5f);
    float4 g4 = *(const float4*)(gam + lane * 4);
    float4 b4 = *(const float4*)(bet + lane * 4);
    float ov[4];
    ov[0] = dx * rstd * g4.x + b4.x;
    ov[1] = dy * rstd * g4.y + b4.y;
    ov[2] = dz * rstd * g4.z + b4.z;
    ov[3] = dw * rstd * g4.w + b4.w;
    u16x4 hv, lv;
    #pragma unroll
    for (int j = 0; j < 4; ++j) {
        hv[j] = f2bf(ov[j]);
        lv[j] = f2bf(ov[j] - bf2f(hv[j]));
    }
    *(u16x4*)(H + (size_t)row * 256 + lane * 4) = hv;
    *(u16x4*)(L + (size_t)row * 256 + lane * 4) = lv;
}

// ---------------------------------------------------------------- MFMA GEMM  y = A @ W.T, K=256
// No LDS in K-loop: A-hi/A-lo/W fragments loaded directly from global
// (each fragment = contiguous 16B in row-major layout). LDS only for the
// coalescing epilogue (MODE 0/2).
template <int MODE>
__global__ __launch_bounds__(256, 3) void gemm_mfma(
    const unsigned short* __restrict__ AH, const unsigned short* __restrict__ AL,
    const unsigned short* __restrict__ Wc, const float* __restrict__ sinT,
    const float* __restrict__ cosT, const float* __restrict__ bias,
    const float* __restrict__ resid, float* __restrict__ F0,
    unsigned short* __restrict__ U0, unsigned short* __restrict__ U1,
    unsigned short* __restrict__ U2, unsigned short* __restrict__ U3,
    unsigned short* __restrict__ U4) {
    __shared__ unsigned short St[128][72];   // epilogue staging only
    const int tid = threadIdx.x;
    const int m0 = blockIdx.y * 128, n0 = blockIdx.x * 128;
    size_t wbase;
    if constexpr (MODE == 0)      wbase = (size_t)(n0 >> 8) * 65536 + (size_t)(n0 & 255) * 256;
    else if constexpr (MODE == 1) wbase = 262144 + (size_t)n0 * 256;
    else if constexpr (MODE == 2) wbase = 327680 + (size_t)n0 * 256;
    else                          wbase = 524288 + (size_t)n0 * 256;

    const int wid = tid >> 6, lane = tid & 63;
    const int wm = wid >> 1, wn = wid & 1;
    const int lr = lane & 15, lk = lane >> 4;

    // per-lane fragment bases (row-major, 16B contiguous per fragment)
    const unsigned short* Ab = AH + (size_t)(m0 + wm * 64 + lr) * 256 + lk * 8;
    const unsigned short* Lb = AL + (size_t)(m0 + wm * 64 + lr) * 256 + lk * 8;
    const unsigned short* Wb = Wc + wbase + (size_t)(wn * 64 + lr) * 256 + lk * 8;

    f32x4 acc[4][4] = {};

    #pragma unroll
    for (int kk = 0; kk < 8; ++kk) {       // 8 k-steps of 32
        const int kof = kk * 32;
        s16x8 af[4], alf[4], bf[4];
        #pragma unroll
        for (int f = 0; f < 4; ++f) {
            af[f]  = *(const s16x8*)(Ab + (size_t)f * 4096 + kof);
            alf[f] = *(const s16x8*)(Lb + (size_t)f * 4096 + kof);
            bf[f]  = *(const s16x8*)(Wb + (size_t)f * 4096 + kof);
        }
        #pragma unroll
        for (int fm = 0; fm < 4; ++fm)
            #pragma unroll
            for (int fn = 0; fn < 4; ++fn) {
                acc[fm][fn] = __builtin_amdgcn_mfma_f32_16x16x32_bf16(af[fm], bf[fn], acc[fm][fn], 0, 0, 0);
                acc[fm][fn] = __builtin_amdgcn_mfma_f32_16x16x32_bf16(alf[fm], bf[fn], acc[fm][fn], 0, 0, 0);
            }
    }

    const int lk4 = lk;  // naming parity with epilogue below
    if constexpr (MODE == 0) {
        const int w = n0 >> 8;  // block-uniform: 0=q 1=k 2=v 3=g
        if (w <= 1) {           // rotary (+ k scaling), in-place on acc
            const float sc = (w == 1) ? SCALING : 1.0f;
            #pragma unroll
            for (int fn = 0; fn < 4; ++fn) {
                const int c = n0 + wn * 64 + fn * 16 + lr;
                const int d0 = c & 31;
                #pragma unroll
                for (int fm = 0; fm < 4; ++fm)
                    #pragma unroll
                    for (int r = 0; r < 4; ++r) {
                        const int i = m0 + wm * 64 + fm * 16 + lk4 * 4 + r;
                        const int t = i % TLEN;
                        float vraw = acc[fm][fn][r] * sc;
                        float oth = __shfl_xor(vraw, 1);
                        float cs = cosT[t * 16 + (d0 >> 1)];
                        float sn = sinT[t * 16 + (d0 >> 1)];
                        acc[fm][fn][r] = (d0 & 1) ? fmaf(vraw, cs, oth * sn)
                                                  : fmaf(vraw, cs, -(oth * sn));
                    }
            }
        }
        unsigned short* Dsel = (w == 0) ? U0 : (w == 1) ? U2 : (w == 2) ? U3 : U4;
        for (int half = 0; half < 2; ++half) {
            const int np = (w == 0) ? 2 : 1;
            for (int pass = 0; pass < np; ++pass) {
                __syncthreads();
                if (wn == half) {
                    #pragma unroll
                    for (int fn = 0; fn < 4; ++fn)
                        #pragma unroll
                        for (int fm = 0; fm < 4; ++fm)
                            #pragma unroll
                            for (int r = 0; r < 4; ++r) {
                                float x = acc[fm][fn][r];
                                unsigned short hb = f2bf(x);
                                unsigned short ob = pass ? f2bf(x - bf2f(hb)) : hb;
                                St[wm * 64 + fm * 16 + lk4 * 4 + r][fn * 16 + lr] = ob;
                            }
                }
                __syncthreads();
                unsigned short* D = (w == 0 && pass) ? U1 : Dsel;
                #pragma unroll
                for (int it = 0; it < 4; ++it) {
                    int flat = it * 2048 + tid * 8;
                    int r = flat >> 6, cl = flat & 63;
                    u16x8 val = *(const u16x8*)&St[r][cl];
                    int i = m0 + r;
                    int cb = (n0 & 255) + half * 64 + cl;
                    if (w <= 2) {
                        int bb = i / TLEN, t = i - bb * TLEN;
                        int hh = cb >> 5, d0 = cb & 31;
                        *(u16x8*)(D + ((size_t)(bb * NHEADS + hh) * TLEN + t) * KD + d0) = val;
                    } else {
                        *(u16x8*)(D + (size_t)i * 256 + cb) = val;
                    }
                }
            }
        }
    } else if constexpr (MODE == 1) {
        #pragma unroll
        for (int fn = 0; fn < 4; ++fn) {
            const int c = n0 + wn * 64 + fn * 16 + lr;
            #pragma unroll
            for (int fm = 0; fm < 4; ++fm)
                #pragma unroll
                for (int r = 0; r < 4; ++r) {
                    const int i = m0 + wm * 64 + fm * 16 + lk4 * 4 + r;
                    F0[(size_t)i * 256 + c] = resid[(size_t)i * 256 + c] + acc[fm][fn][r];
                }
        }
    } else if constexpr (MODE == 2) {
        const int w = n0 >> 8;  // 0=qhat 1=khat 2=vhat
        const float qs = (w == 0) ? SCALING : 1.0f;
        unsigned short* Dsel = (w == 0) ? U0 : (w == 1) ? U1 : U2;
        #pragma unroll
        for (int fn = 0; fn < 4; ++fn) {
            const int c = n0 + wn * 64 + fn * 16 + lr;
            const float bv = bias[c];
            #pragma unroll
            for (int fm = 0; fm < 4; ++fm)
                #pragma unroll
                for (int r = 0; r < 4; ++r)
                    acc[fm][fn][r] = (acc[fm][fn][r] + bv) * qs;
        }
        for (int half = 0; half < 2; ++half) {
            __syncthreads();
            if (wn == half) {
                #pragma unroll
                for (int fn = 0; fn < 4; ++fn)
                    #pragma unroll
                    for (int fm = 0; fm < 4; ++fm)
                        #pragma unroll
                        for (int r = 0; r < 4; ++r)
                            St[wm * 64 + fm * 16 + lk4 * 4 + r][fn * 16 + lr] =
                                f2bf(acc[fm][fn][r]);
            }
            __syncthreads();
            #pragma unroll
            for (int it = 0; it < 4; ++it) {
                int flat = it * 2048 + tid * 8;
                int r = flat >> 6, cl = flat & 63;
                u16x8 val = *(const u16x8*)&St[r][cl];
                int i = m0 + r;
                int cb = (n0 & 255) + half * 64 + cl;
                *(u16x8*)(Dsel + (size_t)i * 256 + cb) = val;
            }
        }
    } else {
        #pragma unroll
        for (int fn = 0; fn < 4; ++fn) {
            const int c = n0 + wn * 64 + fn * 16 + lr;
            const float bv = bias[c];
            #pragma unroll
            for (int fm = 0; fm < 4; ++fm)
                #pragma unroll
                for (int r = 0; r < 4; ++r) {
                    const int i = m0 + wm * 64 + fm * 16 + lk4 * 4 + r;
                    F0[(size_t)i * 256 + c] = resid[(size_t)i * 256 + c] + acc[fm][fn][r] + bv;
                }
        }
    }
}

// ---------------------------------------------------------------- kv partials (2 j-subchunks), bf16 in
__global__ __launch_bounds__(256) void kvp_kernel(const unsigned short* __restrict__ KB,
                                                  const unsigned short* __restrict__ VB,
                                                  float* __restrict__ kvp) {
    int blk = blockIdx.x;
    int sub = blk & 1, rest = blk >> 1;
    int b = rest >> 5, n = (rest >> 3) & 3, h = rest & 7;
    int tid = threadIdx.x;
    int k = tid >> 3, d0 = (tid & 7) * 4;
    float dec = logf(1.0f - exp2f(-5.0f - (float)h));
    float lrs = (1.0f - expf(dec * (float)CHUNKN)) / (1.0f - expf(dec));
    float invl = 1.0f / lrs;
    const unsigned short* krb = KB + ((size_t)(b * NHEADS + h) * TLEN + n * CHUNKN) * KD;
    const unsigned short* vb = VB + ((size_t)(b * NHEADS + h) * TLEN + n * CHUNKN) * KD;
    float a0 = 0, a1 = 0, a2 = 0, a3 = 0;
    int j0 = sub * 250;
    for (int j = j0; j < j0 + 250; ++j) {
        float kj = bf2f(krb[(size_t)j * KD + k]);
        float vd = expf(dec * (float)(CHUNKN - 1 - j)) * invl;
        float w = kj * vd;
        u16x4 vv = *(const u16x4*)(vb + (size_t)j * KD + d0);
        a0 = fmaf(w, bf2f(vv[0]), a0); a1 = fmaf(w, bf2f(vv[1]), a1);
        a2 = fmaf(w, bf2f(vv[2]), a2); a3 = fmaf(w, bf2f(vv[3]), a3);
    }
    float* dst = kvp + ((size_t)rest * 2 + sub) * 1024 + k * 32 + d0;
    dst[0] = a0; dst[1] = a1; dst[2] = a2; dst[3] = a3;
}

// ---------------------------------------------------------------- cross-chunk scan
__global__ __launch_bounds__(256) void scan_kernel(const float* __restrict__ kvp,
                                                   float* __restrict__ rec,
                                                   float* __restrict__ sig) {
    __shared__ float cs[32];
    __shared__ float ssig;
    int blk = blockIdx.x;
    int b = blk >> 3, h = blk & 7;
    int tid = threadIdx.x;
    float dec = logf(1.0f - exp2f(-5.0f - (float)h));
    float cd = expf(dec * (float)CHUNKN);
    float S0 = 0, S1 = 0, S2 = 0, S3 = 0;
    float sigma = 1.0f;
    for (int n = 0; n < NCHUNK; ++n) {
        int rest = b * 32 + n * 8 + h;
        size_t rbase = (size_t)rest * 1024;
        size_t pbase = (size_t)rest * 2048;
        rec[rbase + tid] = S0;
        rec[rbase + tid + 256] = S1;
        rec[rbase + tid + 512] = S2;
        rec[rbase + tid + 768] = S3;
        if (tid == 0) sig[rest] = sigma;
        float k0 = 0, k1 = 0, k2 = 0, k3 = 0;
        #pragma unroll
        for (int s = 0; s < 2; ++s) {
            k0 += kvp[pbase + s * 1024 + tid];
            k1 += kvp[pbase + s * 1024 + tid + 256];
            k2 += kvp[pbase + s * 1024 + tid + 512];
            k3 += kvp[pbase + s * 1024 + tid + 768];
        }
        S0 = S0 * cd + k0;
        S1 = S1 * cd + k1;
        S2 = S2 * cd + k2;
        S3 = S3 * cd + k3;
        if (tid < 32) cs[tid] = 0.f;
        __syncthreads();
        float part = fabsf(S0) + fabsf(S1) + fabsf(S2) + fabsf(S3);
        atomicAdd(&cs[tid & 31], part);
        __syncthreads();
        if (tid == 0) {
            float m = cs[0];
            for (int d = 1; d < 32; ++d) m = fmaxf(m, cs[d]);
            ssig = fmaxf(m, 1.0f);
        }
        __syncthreads();
        sigma = ssig;
    }
}

// ---------------------------------------------------------------- retention core v3 (MFMA, bf16 in)
__global__ __launch_bounds__(256, 2) void ret_core3(
    const unsigned short* __restrict__ QH, const unsigned short* __restrict__ QL,
    const unsigned short* __restrict__ KB, const unsigned short* __restrict__ VB,
    const unsigned short* __restrict__ GB,
    const float* __restrict__ rec, const float* __restrict__ sig,
    unsigned short* __restrict__ ABH, unsigned short* __restrict__ ABL) {
    __shared__ unsigned short Kt[64][40];    // K*e^{-dec j}  [j][d]
    __shared__ unsigned short Vt[32][72];    // V^T           [d][j]
    __shared__ unsigned short SpH[32][40];   // S_prev^T hi   [d][k]
    __shared__ unsigned short SpL[32][40];   // S_prev^T lo
    __shared__ unsigned short Pl[128][72];   // P (loop) / out hi+lo (epilogue)

    const int u = 3 - (int)(blockIdx.x >> 8);
    const int chunk = blockIdx.x & 255;
    const int b = chunk >> 5, n = (chunk >> 3) & 3, h = chunk & 7;
    const int tid = threadIdx.x;
    const int wid = tid >> 6, lane = tid & 63;
    const int c = lane & 15, gq = lane >> 4;
    const float dec = logf(1.0f - exp2f(-5.0f - (float)h));
    const float ndec = -dec;
    const size_t cb16 = ((size_t)(b * NHEADS + h) * TLEN + n * CHUNKN) * KD;
    const int i0 = u * 128 + wid * 32;
    const int NT = 2 * u + 2;
    const int jtmax_w = (i0 + 31) >> 6;

    // ---- Q fragments: direct bf16 hi/lo loads
    s16x8 qh[2], ql[2];
    #pragma unroll
    for (int fi = 0; fi < 2; ++fi) {
        size_t off = cb16 + (size_t)(i0 + fi * 16 + c) * KD + gq * 8;
        qh[fi] = *(const s16x8*)(QH + off);
        ql[fi] = *(const s16x8*)(QL + off);
    }

    // ---- stage S_prev^T hi/lo (rec is [k][d] row-major fp32, 32x32)
    {
        int e0 = tid * 4;
        int k = e0 >> 5, d0 = e0 & 31;
        float4 sv = *(const float4*)(rec + (size_t)chunk * 1024 + e0);
        float se[4] = {sv.x, sv.y, sv.z, sv.w};
        #pragma unroll
        for (int j = 0; j < 4; ++j) {
            unsigned short hb = f2bf(se[j]);
            SpH[d0 + j][k] = hb;
            SpL[d0 + j][k] = f2bf(se[j] - bf2f(hb));
        }
    }

    f32x4 ot[2][2] = {};
    float absI[2] = {0.f, 0.f};

    for (int jt = 0; jt < NT; ++jt) {
        if (jt) __syncthreads();
        {   // stage K (scaled) and V^T from bf16
            int jl = tid >> 2, d0 = (tid & 3) * 8;
            int jg = jt * 64 + jl;
            float ej = expf(ndec * (float)jg);
            u16x8 kraw = *(const u16x8*)(KB + cb16 + (size_t)jg * KD + d0);
            u16x8 vraw = *(const u16x8*)(VB + cb16 + (size_t)jg * KD + d0);
            u16x8 kb;
            #pragma unroll
            for (int e = 0; e < 8; ++e) kb[e] = f2bf(bf2f(kraw[e]) * ej);
            *(u16x8*)&Kt[jl][d0] = kb;
            #pragma unroll
            for (int e = 0; e < 8; ++e) Vt[d0 + e][jl] = vraw[e];
        }
        __syncthreads();
        if (jt <= jtmax_w) {
            f32x4 st[4][2] = {};
            s16x8 ka[4];
            #pragma unroll
            for (int jf = 0; jf < 4; ++jf)
                ka[jf] = *(const s16x8*)&Kt[jf * 16 + c][gq * 8];
            #pragma unroll
            for (int jf = 0; jf < 4; ++jf)
                #pragma unroll
                for (int fi = 0; fi < 2; ++fi) {
                    st[jf][fi] = __builtin_amdgcn_mfma_f32_16x16x32_bf16(ka[jf], qh[fi], st[jf][fi], 0, 0, 0);
                    st[jf][fi] = __builtin_amdgcn_mfma_f32_16x16x32_bf16(ka[jf], ql[fi], st[jf][fi], 0, 0, 0);
                }
            const bool domask = (jt * 64 + 63 > i0);
            #pragma unroll
            for (int jf = 0; jf < 4; ++jf)
                #pragma unroll
                for (int fi = 0; fi < 2; ++fi) {
                    const int ii = i0 + fi * 16 + c;
                    if (domask) {
                        #pragma unroll
                        for (int r = 0; r < 4; ++r) {
                            int jg = jt * 64 + jf * 16 + gq * 4 + r;
                            if (jg > ii) st[jf][fi][r] = 0.f;
                        }
                    }
                    absI[fi] += (fabsf(st[jf][fi][0]) + fabsf(st[jf][fi][1])) +
                                (fabsf(st[jf][fi][2]) + fabsf(st[jf][fi][3]));
                    uint2 pw;
                    pw.x = cvtpk(st[jf][fi][0], st[jf][fi][1]);
                    pw.y = cvtpk(st[jf][fi][2], st[jf][fi][3]);
                    *(uint2*)&Pl[wid * 32 + fi * 16 + c][jf * 16 + gq * 4] = pw;
                }
            #pragma unroll
            for (int js = 0; js < 2; ++js) {
                s16x8 va0 = *(const s16x8*)&Vt[c][js * 32 + gq * 8];
                s16x8 va1 = *(const s16x8*)&Vt[16 + c][js * 32 + gq * 8];
                #pragma unroll
                for (int fi = 0; fi < 2; ++fi) {
                    s16x8 pb = *(const s16x8*)&Pl[wid * 32 + fi * 16 + c][js * 32 + gq * 8];
                    ot[0][fi] = __builtin_amdgcn_mfma_f32_16x16x32_bf16(va0, pb, ot[0][fi], 0, 0, 0);
                    ot[1][fi] = __builtin_amdgcn_mfma_f32_16x16x32_bf16(va1, pb, ot[1][fi], 0, 0, 0);
                }
            }
        }
    }

    // ---- cross term X^T = S_prev^T · Q
    f32x4 xt[2][2] = {};
    #pragma unroll
    for (int fd = 0; fd < 2; ++fd) {
        s16x8 sh = *(const s16x8*)&SpH[fd * 16 + c][gq * 8];
        s16x8 sl = *(const s16x8*)&SpL[fd * 16 + c][gq * 8];
        #pragma unroll
        for (int fi = 0; fi < 2; ++fi) {
            xt[fd][fi] = __builtin_amdgcn_mfma_f32_16x16x32_bf16(sh, qh[fi], xt[fd][fi], 0, 0, 0);
            xt[fd][fi] = __builtin_amdgcn_mfma_f32_16x16x32_bf16(sh, ql[fi], xt[fd][fi], 0, 0, 0);
            xt[fd][fi] = __builtin_amdgcn_mfma_f32_16x16x32_bf16(sl, qh[fi], xt[fd][fi], 0, 0, 0);
        }
    }

    // ---- per-row scales + combine + group-norm + silu(g bf16) -> Pl
    const float er = expf(dec);
    const float inv1mr = 1.0f / (1.0f - er);
    const float lrs = (1.0f - expf(dec * (float)CHUNKN)) * inv1mr;
    const float sgp = sig[chunk];
    #pragma unroll
    for (int fi = 0; fi < 2; ++fi) {
        absI[fi] += __shfl_xor(absI[fi], 16);
        absI[fi] += __shfl_xor(absI[fi], 32);
        const int ii = i0 + fi * 16 + c;
        float rowsum = (1.0f - expf(dec * (float)(ii + 1))) * inv1mr;
        float iscale = rsqrtf(rowsum);
        float f_i = expf(dec * (float)ii) * iscale;
        float inner = fmaxf(absI[fi] * f_i, 1.0f);
        float alls = fmaxf(inner, sgp);
        float qd = expf(dec * (float)(ii + 1)) * lrs * iscale;
        float inva = 1.0f / alls;
        float vals[2][4];
        float ms = 0.f;
        #pragma unroll
        for (int fd = 0; fd < 2; ++fd)
            #pragma unroll
            for (int r = 0; r < 4; ++r) {
                float t = (ot[fd][fi][r] * f_i + xt[fd][fi][r] * qd) * inva;
                vals[fd][r] = t;
                ms += t * t;
            }
        ms += __shfl_xor(ms, 16);
        ms += __shfl_xor(ms, 32);
        float rn = rsqrtf(ms * (1.0f / 32.0f) + 1e-6f);
        const int tg = n * CHUNKN + ii;
        const unsigned short* gp = GB + ((size_t)b * TLEN + tg) * 256 + h * KD;
        #pragma unroll
        for (int fd = 0; fd < 2; ++fd) {
            u16x4 gv = *(const u16x4*)(gp + fd * 16 + gq * 4);
            unsigned short hb[4], lb[4];
            #pragma unroll
            for (int r = 0; r < 4; ++r) {
                float ge = bf2f(gv[r]);
                float sg = ge / (1.0f + expf(-ge));
                float ov = sg * vals[fd][r] * rn;
                hb[r] = f2bf(ov);
                lb[r] = f2bf(ov - bf2f(hb[r]));
            }
            uint2 ph, plw;
            ph.x = (unsigned int)hb[0] | ((unsigned int)hb[1] << 16);
            ph.y = (unsigned int)hb[2] | ((unsigned int)hb[3] << 16);
            plw.x = (unsigned int)lb[0] | ((unsigned int)lb[1] << 16);
            plw.y = (unsigned int)lb[2] | ((unsigned int)lb[3] << 16);
            *(uint2*)&Pl[wid * 32 + fi * 16 + c][fd * 16 + gq * 4] = ph;
            *(uint2*)&Pl[wid * 32 + fi * 16 + c][36 + fd * 16 + gq * 4] = plw;
        }
    }
    __syncthreads();
    {
        int r = tid & 127, half = tid >> 7;
        int ig = u * 128 + r;
        if (ig < CHUNKN) {
            unsigned short* D = half ? ABL : ABH;
            size_t dst = ((size_t)b * TLEN + n * CHUNKN + ig) * 256 + h * KD;
            #pragma unroll
            for (int k = 0; k < 4; ++k) {
                u16x4 a = *(const u16x4*)&Pl[r][half * 36 + k * 8];
                u16x4 bq = *(const u16x4*)&Pl[r][half * 36 + k * 8 + 4];
                u16x8 w;
                w[0] = a[0]; w[1] = a[1]; w[2] = a[2]; w[3] = a[3];
                w[4] = bq[0]; w[5] = bq[1]; w[6] = bq[2]; w[7] = bq[3];
                *(u16x8*)(D + dst + k * 8) = w;
            }
        }
    }
}

// ---------------------------------------------------------------- tiny MHA (seq len 4), bf16 in -> bf16 hi/lo out
__global__ __launch_bounds__(256) void mha_attn(const unsigned short* __restrict__ qh_,
                                                const unsigned short* __restrict__ kh_,
                                                const unsigned short* __restrict__ vh_,
                                                unsigned short* __restrict__ OH,
                                                unsigned short* __restrict__ OL) {
    int gidx = blockIdx.x * 256 + threadIdx.x;
    if (gidx >= 2 * TLEN * NHEADS * 4) return;
    int i = gidx & 3;
    int h = (gidx >> 2) & 7;
    int rest = gidx >> 5;  // b*2000 + t
    int t = rest % TLEN;
    int b = rest / TLEN;
    size_t rows[4];
    #pragma unroll
    for (int c = 0; c < 4; ++c) rows[c] = ((size_t)(b * 4 + c) * TLEN + t);
    float q[32];
    #pragma unroll
    for (int rb = 0; rb < 4; ++rb) {
        u16x8 t8 = *(const u16x8*)(qh_ + rows[i] * 256 + h * 32 + rb * 8);
        #pragma unroll
        for (int e = 0; e < 8; ++e) q[rb * 8 + e] = bf2f(t8[e]);
    }
    float s[4];
    #pragma unroll
    for (int j = 0; j < 4; ++j) {
        const unsigned short* kp = kh_ + rows[j] * 256 + h * 32;
        float a0 = 0, a1 = 0, a2 = 0, a3 = 0;
        #pragma unroll
        for (int rb = 0; rb < 4; ++rb) {
            u16x8 t8 = *(const u16x8*)(kp + rb * 8);
            a0 = fmaf(q[rb * 8 + 0], bf2f(t8[0]), a0);
            a1 = fmaf(q[rb * 8 + 1], bf2f(t8[1]), a1);
            a2 = fmaf(q[rb * 8 + 2], bf2f(t8[2]), a2);
            a3 = fmaf(q[rb * 8 + 3], bf2f(t8[3]), a3);
            a0 = fmaf(q[rb * 8 + 4], bf2f(t8[4]), a0);
            a1 = fmaf(q[rb * 8 + 5], bf2f(t8[5]), a1);
            a2 = fmaf(q[rb * 8 + 6], bf2f(t8[6]), a2);
            a3 = fmaf(q[rb * 8 + 7], bf2f(t8[7]), a3);
        }
        s[j] = (a0 + a1) + (a2 + a3);
    }
    float m = fmaxf(fmaxf(s[0], s[1]), fmaxf(s[2], s[3]));
    float p[4], den = 0.f;
    #pragma unroll
    for (int j = 0; j < 4; ++j) { p[j] = expf(s[j] - m); den += p[j]; }
    float inv = 1.0f / den;
    float o[32];
    #pragma unroll
    for (int e = 0; e < 32; ++e) o[e] = 0.f;
    #pragma unroll
    for (int j = 0; j < 4; ++j) {
        float wj = p[j] * inv;
        const unsigned short* vp = vh_ + rows[j] * 256 + h * 32;
        #pragma unroll
        for (int rb = 0; rb < 4; ++rb) {
            u16x8 t8 = *(const u16x8*)(vp + rb * 8);
            #pragma unroll
            for (int e = 0; e < 8; ++e)
                o[rb * 8 + e] = fmaf(wj, bf2f(t8[e]), o[rb * 8 + e]);
        }
    }
    #pragma unroll
    for (int rb = 0; rb < 8; ++rb) {
        u16x4 hv, lv;
        #pragma unroll
        for (int e = 0; e < 4; ++e) {
            float x = o[rb * 4 + e];
            hv[e] = f2bf(x);
            lv[e] = f2bf(x - bf2f(hv[e]));
        }
        *(u16x4*)(OH + rows[i] * 256 + h * 32 + rb * 4) = hv;
        *(u16x4*)(OL + rows[i] * 256 + h * 32 + rb * 4) = lv;
    }
}

// ---------------------------------------------------------------- launch
extern "C" void kernel_launch(void* const* d_in, const int* in_sizes, int n_in,
                              void* d_out, int out_size, void* d_ws, size_t ws_size,
                              hipStream_t stream) {
    (void)in_sizes; (void)n_in; (void)out_size; (void)ws_size;
    const float* x    = (const float*)d_in[0];
    const float* ln1g = (const float*)d_in[1];
    const float* ln1b = (const float*)d_in[2];
    const float* ln2g = (const float*)d_in[3];
    const float* ln2b = (const float*)d_in[4];
    const float* qw   = (const float*)d_in[5];
    const float* kw   = (const float*)d_in[6];
    const float* vw   = (const float*)d_in[7];
    const float* gw   = (const float*)d_in[8];
    const float* ow   = (const float*)d_in[9];
    const float* in_w = (const float*)d_in[10];
    const float* in_b = (const float*)d_in[11];
    const float* outw = (const float*)d_in[12];
    const float* outb = (const float*)d_in[13];
    float* out = (float*)d_out;
    float* ws = (float*)d_ws;

    // workspace layout (float units), total 14,957,312 fl = 59.8 MB
    constexpr size_t O_SIN = 0;                    // 32000
    constexpr size_t O_COS = 32000;                // 32000
    constexpr size_t O_W   = 64000;                // 294912 (bf16 weights)
    constexpr size_t O_QH  = 358912;               // 2048000 | x2 overlay (QH+QL)
    constexpr size_t O_QL  = O_QH + 2048000;       // 2048000
    constexpr size_t O_KB  = O_QL + 2048000;       // 2048000 | qhat overlay
    constexpr size_t O_VB  = O_KB + 2048000;       // 2048000 | khat overlay
    constexpr size_t O_GB  = O_VB + 2048000;       // 2048000 | vhat overlay
    constexpr size_t O_H   = O_GB + 2048000;       // 2048000 | kvp overlay
    constexpr size_t O_L   = O_H + 2048000;        // 2048000
    constexpr size_t O_REC = O_L + 2048000;        // 262144
    constexpr size_t O_SIG = O_REC + 262144;       // 256

    float* sinT = ws + O_SIN;
    float* cosT = ws + O_COS;
    unsigned short* Wc = (unsigned short*)(ws + O_W);
    unsigned short* QH = (unsigned short*)(ws + O_QH);
    unsigned short* QL = (unsigned short*)(ws + O_QL);
    unsigned short* KB = (unsigned short*)(ws + O_KB);
    unsigned short* VB = (unsigned short*)(ws + O_VB);
    unsigned short* GB = (unsigned short*)(ws + O_GB);
    unsigned short* H  = (unsigned short*)(ws + O_H);
    unsigned short* L  = (unsigned short*)(ws + O_L);
    float* x2   = ws + O_QH;   // overlay QH+QL (dead after ret_core3)
    unsigned short* qhat = KB; // overlays dead after ret_core3
    unsigned short* khat = VB;
    unsigned short* vhat = GB;
    float* kvpf = ws + O_H;    // overlay H (dead between proj and ret_core3)
    float* recb = ws + O_REC;
    float* sigb = ws + O_SIG;

    tab_kernel<<<125, 256, 0, stream>>>(sinT, cosT);
    wcast_kernel<<<576, 256, 0, stream>>>(qw, kw, vw, gw, ow, in_w, outw, Wc);
    // 1) LN1: x -> H/L
    ln_kernel<<<MROWS / 4, 256, 0, stream>>>(x, ln1g, ln1b, H, L, MROWS);
    // 2) proj -> QH/QL (q hi/lo), KB, VB (head layout), GB (row layout)
    gemm_mfma<0><<<dim3(8, 125), 256, 0, stream>>>(H, L, Wc, sinT, cosT, nullptr,
                                                   nullptr, nullptr, QH, QL, KB, VB, GB);
    // 3) kv partials (bf16 in) -> kvpf
    kvp_kernel<<<512, 256, 0, stream>>>(KB, VB, kvpf);
    // 4) scan -> rec, sig
    scan_kernel<<<64, 256, 0, stream>>>(kvpf, recb, sigb);
    // 5) retention core -> H/L (ab hi/lo)
    ret_core3<<<1024, 256, 0, stream>>>(QH, QL, KB, VB, GB, recb, sigb, H, L);
    // 6) out-proj + residual -> x2
    gemm_mfma<1><<<dim3(2, 125), 256, 0, stream>>>(H, L, Wc, nullptr, nullptr,
                                                   nullptr, x, x2,
                                                   nullptr, nullptr, nullptr, nullptr, nullptr);
    // 7) LN2: x2 -> H/L
    ln_kernel<<<MROWS / 4, 256, 0, stream>>>(x2, ln2g, ln2b, H, L, MROWS);
    // 8) qkv -> qhat/khat/vhat (bf16 row layout)
    gemm_mfma<2><<<dim3(6, 125), 256, 0, stream>>>(H, L, Wc, nullptr, nullptr,
                                                   in_b, nullptr, nullptr,
                                                   qhat, khat, vhat, nullptr, nullptr);
    // 9) tiny attention -> H/L (att hi/lo)
    mha_attn<<<500, 256, 0, stream>>>(qhat, khat, vhat, H, L);
    // 10) final: x2 + att @ out_w.T + out_b -> d_out
    gemm_mfma<3><<<dim3(2, 125), 256, 0, stream>>>(H, L, Wc, nullptr, nullptr,
                                                   outb, x2, out,
                                                   nullptr, nullptr, nullptr, nullptr, nullptr);
}